// Round 1
// baseline (242.620 us; speedup 1.0000x reference)
//
#include <hip/hip_runtime.h>
#include <hip/hip_bf16.h>
#include <stdint.h>

#define B_ 2
#define S_ 2048
#define D_ 1024
#define H_ 16
#define HD_ 64
#define KJL 32
#define N3 3072

typedef __attribute__((ext_vector_type(8))) __bf16 bf16x8;
typedef __attribute__((ext_vector_type(4))) float floatx4;
typedef __attribute__((ext_vector_type(4))) short short4v;

__device__ __forceinline__ unsigned short f2b(float x) {
  union { float f; unsigned u; } v; v.f = x;
  unsigned r = v.u + 0x7fffu + ((v.u >> 16) & 1u);
  return (unsigned short)(r >> 16);
}

__device__ __forceinline__ void async16(const void* g, void* l) {
  __builtin_amdgcn_global_load_lds((__attribute__((address_space(1))) void*)(g),
                                   (__attribute__((address_space(3))) void*)(l),
                                   16, 0, 0);
}

// ---------------- fp32 -> bf16 elementwise convert ----------------
__global__ void cvt_kernel(const float* __restrict__ in,
                           unsigned short* __restrict__ out, int n) {
  int i = blockIdx.x * blockDim.x + threadIdx.x;
  int stride = gridDim.x * blockDim.x;
  for (; i < n; i += stride) out[i] = f2b(in[i]);
}

// ------------- fp32 [R][C] -> bf16 [C][R] transpose-convert -------------
__global__ void tcvt_kernel(const float* __restrict__ in,
                            unsigned short* __restrict__ out, int R, int C) {
  __shared__ float t[32][33];
  int c0 = blockIdx.x * 32, r0 = blockIdx.y * 32;
  int tx = threadIdx.x, ty = threadIdx.y;
  for (int j = 0; j < 32; j += 8)
    t[ty + j][tx] = in[(r0 + ty + j) * C + c0 + tx];
  __syncthreads();
  for (int j = 0; j < 32; j += 8)
    out[(c0 + ty + j) * R + r0 + tx] = f2b(t[tx][ty + j]);
}

// ---------------- qkv GEMM: hB[4096,1024] @ WaT^T -> Q/K/V ----------------
// Bt is W_attn transposed: [3072][1024] bf16. Outputs:
//  Qh,Kh: [B,H,S,HD] bf16 (bias added), Vt: [B,H,HD,S] bf16 (transposed V)
__global__ __launch_bounds__(256, 2)
void qkv_gemm_kernel(const unsigned short* __restrict__ A,
                     const unsigned short* __restrict__ Bt,
                     const float* __restrict__ bias,
                     unsigned short* __restrict__ Qh,
                     unsigned short* __restrict__ Kh,
                     unsigned short* __restrict__ Vt) {
  __shared__ __align__(16) unsigned short As[128 * 32];
  __shared__ __align__(16) unsigned short Bs[128 * 32];
  const int tid = threadIdx.x;
  const int lane = tid & 63, wv = tid >> 6;
  const int quad = lane >> 4, col = lane & 15;
  const int wm = wv >> 1, wn = wv & 1;
  const int m0 = blockIdx.y * 128, n0 = blockIdx.x * 128;

  floatx4 acc[4][4] = {};

  for (int kk = 0; kk < D_; kk += 32) {
    for (int it = 0; it < 2; ++it) {
      int c = it * 256 + tid;          // 0..511 chunks of 16B
      int row = c >> 2, k8 = (c & 3) << 3;
      async16(A + (m0 + row) * D_ + kk + k8, &As[c * 8]);
      async16(Bt + (n0 + row) * D_ + kk + k8, &Bs[c * 8]);
    }
    asm volatile("s_waitcnt vmcnt(0)" ::: "memory");
    __syncthreads();
    bf16x8 af[4], bfr[4];
    for (int mt = 0; mt < 4; ++mt)
      af[mt] = *(const bf16x8*)&As[(wm * 64 + mt * 16 + col) * 32 + quad * 8];
    for (int nt = 0; nt < 4; ++nt)
      bfr[nt] = *(const bf16x8*)&Bs[(wn * 64 + nt * 16 + col) * 32 + quad * 8];
    for (int mt = 0; mt < 4; ++mt)
      for (int nt = 0; nt < 4; ++nt)
        acc[mt][nt] = __builtin_amdgcn_mfma_f32_16x16x32_bf16(
            af[mt], bfr[nt], acc[mt][nt], 0, 0, 0);
    __syncthreads();
  }

  const int part = n0 >> 10;  // whole block is within one of q/k/v
  for (int mt = 0; mt < 4; ++mt) {
    int gm0 = m0 + wm * 64 + mt * 16 + quad * 4;
    int b = gm0 >> 11, s = gm0 & (S_ - 1);
    for (int nt = 0; nt < 4; ++nt) {
      int gn = n0 + wn * 64 + nt * 16 + col;
      float bs = bias[gn];
      int h = (gn >> 6) & (H_ - 1);
      int hd = gn & (HD_ - 1);
      if (part == 2) {
        short4v vv;
        for (int i = 0; i < 4; ++i) {
          unsigned short u = f2b(acc[mt][nt][i] + bs);
          vv[i] = (short)u;
        }
        *(short4v*)&Vt[((b * H_ + h) * HD_ + hd) * S_ + s] = vv;
      } else {
        unsigned short* dst = (part == 0) ? Qh : Kh;
        int base = ((b * H_ + h) * S_ + s) * HD_ + hd;
        for (int i = 0; i < 4; ++i)
          dst[base + i * HD_] = f2b(acc[mt][nt][i] + bs);
      }
    }
  }
}

// ---------------- JL projection: X[65536,64] @ Sp^T -> Y[65536,32] ----------------
__global__ __launch_bounds__(256)
void jl_kernel(const unsigned short* __restrict__ X,
               const unsigned short* __restrict__ Sp,  // [32][64] bf16
               unsigned short* __restrict__ Y, float scale) {
  const int tid = threadIdx.x;
  const int lane = tid & 63, wv = tid >> 6;
  const int quad = lane >> 4, col = lane & 15;
  const int rowbase = blockIdx.x * 256 + wv * 64;
  bf16x8 bfr[2][2];
  for (int nt = 0; nt < 2; ++nt)
    for (int ks = 0; ks < 2; ++ks)
      bfr[nt][ks] = *(const bf16x8*)&Sp[(nt * 16 + col) * 64 + ks * 32 + quad * 8];
  for (int mt = 0; mt < 4; ++mt) {
    floatx4 acc[2] = {};
    for (int ks = 0; ks < 2; ++ks) {
      bf16x8 af = *(const bf16x8*)&X[(rowbase + mt * 16 + col) * 64 + ks * 32 + quad * 8];
      for (int nt = 0; nt < 2; ++nt)
        acc[nt] = __builtin_amdgcn_mfma_f32_16x16x32_bf16(af, bfr[nt][ks], acc[nt], 0, 0, 0);
    }
    for (int nt = 0; nt < 2; ++nt)
      for (int i = 0; i < 4; ++i)
        Y[(rowbase + mt * 16 + quad * 4 + i) * 32 + nt * 16 + col] =
            f2b(acc[nt][i] * scale);
  }
}

// ---------------- flash attention ----------------
// Qjl/Kjl: [BH,2048,32] bf16 (Qjl pre-scaled by 1/8), Vt: [BH,64,2048] bf16
// AO: merged [B,2048,1024] bf16
__global__ __launch_bounds__(256, 2)
void attn_kernel(const unsigned short* __restrict__ Qjl,
                 const unsigned short* __restrict__ Kjl,
                 const unsigned short* __restrict__ Vt,
                 unsigned short* __restrict__ AO) {
  __shared__ __align__(16) unsigned short Qs[128 * 32];
  __shared__ __align__(16) unsigned short Ks[128 * 32];
  __shared__ __align__(16) unsigned short Vs[64 * 136];   // pad 128->136
  __shared__ __align__(16) unsigned short Ps[128 * 136];  // pad 128->136
  const int tid = threadIdx.x;
  const int lane = tid & 63, wv = tid >> 6;
  const int quad = lane >> 4, col = lane & 15;
  const int qt = blockIdx.x, h = blockIdx.y, b = blockIdx.z;
  const int bh = b * H_ + h;
  const unsigned short* Qg = Qjl + (bh * S_ + qt * 128) * KJL;

  floatx4 o[2][4] = {};
  float mrow[2][4], lrow[2][4];
  for (int mt = 0; mt < 2; ++mt)
    for (int i = 0; i < 4; ++i) { mrow[mt][i] = -1e30f; lrow[mt][i] = 0.f; }

  for (int kt = 0; kt <= qt; ++kt) {
    const unsigned short* Kg = Kjl + (bh * S_ + kt * 128) * KJL;
    for (int it = 0; it < 2; ++it) {
      int c = it * 256 + tid;
      async16(Kg + c * 8, &Ks[c * 8]);
      if (kt == 0) async16(Qg + c * 8, &Qs[c * 8]);
    }
    for (int j = 0; j < 4; ++j) {           // V tile -> LDS with padding
      int c = j * 256 + tid;                // 0..1023
      int row = c >> 4, c16 = c & 15;
      bf16x8 v = *(const bf16x8*)&Vt[(bh * HD_ + row) * S_ + kt * 128 + c16 * 8];
      *(bf16x8*)&Vs[row * 136 + c16 * 8] = v;
    }
    asm volatile("s_waitcnt vmcnt(0)" ::: "memory");
    __syncthreads();

    // QK^T: wave wv owns q rows [wv*32, wv*32+32)
    bf16x8 aq[2];
    for (int mt = 0; mt < 2; ++mt)
      aq[mt] = *(const bf16x8*)&Qs[(wv * 32 + mt * 16 + col) * 32 + quad * 8];
    floatx4 sc[2][8];
    for (int nt = 0; nt < 8; ++nt) {
      bf16x8 bk = *(const bf16x8*)&Ks[(nt * 16 + col) * 32 + quad * 8];
      floatx4 z = {0.f, 0.f, 0.f, 0.f};
      for (int mt = 0; mt < 2; ++mt)
        sc[mt][nt] = __builtin_amdgcn_mfma_f32_16x16x32_bf16(aq[mt], bk, z, 0, 0, 0);
    }

    if (kt == qt) {  // causal mask, diagonal tile only
      for (int mt = 0; mt < 2; ++mt)
        for (int i = 0; i < 4; ++i) {
          int q = wv * 32 + mt * 16 + quad * 4 + i;
          for (int nt = 0; nt < 8; ++nt)
            if (nt * 16 + col > q) sc[mt][nt][i] = -1e30f;
        }
    }

    // online softmax per q row (row lives in 16 lanes of one quad)
    for (int mt = 0; mt < 2; ++mt) {
      for (int i = 0; i < 4; ++i) {
        float vmax = sc[mt][0][i];
        for (int nt = 1; nt < 8; ++nt) vmax = fmaxf(vmax, sc[mt][nt][i]);
        for (int off = 1; off < 16; off <<= 1)
          vmax = fmaxf(vmax, __shfl_xor(vmax, off, 64));
        float mnew = fmaxf(mrow[mt][i], vmax);
        float alpha = __expf(mrow[mt][i] - mnew);
        float rsum = 0.f;
        for (int nt = 0; nt < 8; ++nt) {
          float p = __expf(sc[mt][nt][i] - mnew);
          sc[mt][nt][i] = p;
          rsum += p;
        }
        for (int off = 1; off < 16; off <<= 1)
          rsum += __shfl_xor(rsum, off, 64);
        lrow[mt][i] = lrow[mt][i] * alpha + rsum;
        mrow[mt][i] = mnew;
        for (int nh = 0; nh < 4; ++nh) o[mt][nh][i] *= alpha;
      }
      for (int nt = 0; nt < 8; ++nt)
        for (int i = 0; i < 4; ++i)
          Ps[(wv * 32 + mt * 16 + quad * 4 + i) * 136 + nt * 16 + col] =
              f2b(sc[mt][nt][i]);
    }

    // PV: o += P @ V
    for (int mt = 0; mt < 2; ++mt)
      for (int ks = 0; ks < 4; ++ks) {
        bf16x8 ap = *(const bf16x8*)&Ps[(wv * 32 + mt * 16 + col) * 136 + ks * 32 + quad * 8];
        for (int nh = 0; nh < 4; ++nh) {
          bf16x8 bv = *(const bf16x8*)&Vs[(nh * 16 + col) * 136 + ks * 32 + quad * 8];
          o[mt][nh] = __builtin_amdgcn_mfma_f32_16x16x32_bf16(ap, bv, o[mt][nh], 0, 0, 0);
        }
      }
    __syncthreads();
  }

  for (int mt = 0; mt < 2; ++mt)
    for (int i = 0; i < 4; ++i) {
      float inv = 1.f / lrow[mt][i];
      int s = qt * 128 + wv * 32 + mt * 16 + quad * 4 + i;
      for (int nh = 0; nh < 4; ++nh) {
        int d = h * HD_ + nh * 16 + col;
        AO[(b * S_ + s) * D_ + d] = f2b(o[mt][nh][i] * inv);
      }
    }
}

// ---------------- output projection: AO[4096,1024] @ WpT^T + b -> fp32 out ----------------
__global__ __launch_bounds__(256, 2)
void proj_gemm_kernel(const unsigned short* __restrict__ A,
                      const unsigned short* __restrict__ Bt,  // [1024][1024]
                      const float* __restrict__ bias,
                      float* __restrict__ out) {
  __shared__ __align__(16) unsigned short As[128 * 32];
  __shared__ __align__(16) unsigned short Bs[128 * 32];
  const int tid = threadIdx.x;
  const int lane = tid & 63, wv = tid >> 6;
  const int quad = lane >> 4, col = lane & 15;
  const int wm = wv >> 1, wn = wv & 1;
  const int m0 = blockIdx.y * 128, n0 = blockIdx.x * 128;

  floatx4 acc[4][4] = {};

  for (int kk = 0; kk < D_; kk += 32) {
    for (int it = 0; it < 2; ++it) {
      int c = it * 256 + tid;
      int row = c >> 2, k8 = (c & 3) << 3;
      async16(A + (m0 + row) * D_ + kk + k8, &As[c * 8]);
      async16(Bt + (n0 + row) * D_ + kk + k8, &Bs[c * 8]);
    }
    asm volatile("s_waitcnt vmcnt(0)" ::: "memory");
    __syncthreads();
    bf16x8 af[4], bfr[4];
    for (int mt = 0; mt < 4; ++mt)
      af[mt] = *(const bf16x8*)&As[(wm * 64 + mt * 16 + col) * 32 + quad * 8];
    for (int nt = 0; nt < 4; ++nt)
      bfr[nt] = *(const bf16x8*)&Bs[(wn * 64 + nt * 16 + col) * 32 + quad * 8];
    for (int mt = 0; mt < 4; ++mt)
      for (int nt = 0; nt < 4; ++nt)
        acc[mt][nt] = __builtin_amdgcn_mfma_f32_16x16x32_bf16(
            af[mt], bfr[nt], acc[mt][nt], 0, 0, 0);
    __syncthreads();
  }

  for (int mt = 0; mt < 4; ++mt) {
    int gm0 = m0 + wm * 64 + mt * 16 + quad * 4;
    for (int nt = 0; nt < 4; ++nt) {
      int gn = n0 + wn * 64 + nt * 16 + col;
      float bs = bias[gn];
      for (int i = 0; i < 4; ++i)
        out[(gm0 + i) * D_ + gn] = acc[mt][nt][i] + bs;
    }
  }
}

extern "C" void kernel_launch(void* const* d_in, const int* in_sizes, int n_in,
                              void* d_out, int out_size, void* d_ws, size_t ws_size,
                              hipStream_t stream) {
  (void)in_sizes; (void)n_in; (void)out_size; (void)ws_size;
  const float* hidden = (const float*)d_in[0];
  const float* W_attn = (const float*)d_in[1];
  const float* b_attn = (const float*)d_in[2];
  const float* S_proj = (const float*)d_in[3];
  const float* W_proj = (const float*)d_in[4];
  const float* b_proj = (const float*)d_in[5];
  float* out = (float*)d_out;

  char* ws = (char*)d_ws;
  unsigned short* hB  = (unsigned short*)(ws);              //  8 MB
  unsigned short* WaT = (unsigned short*)(ws + 8388608);    //  6 MB
  unsigned short* WpT = (unsigned short*)(ws + 14680064);   //  2 MB
  unsigned short* Qh  = (unsigned short*)(ws + 16777216);   //  8 MB
  unsigned short* Kh  = (unsigned short*)(ws + 25165824);   //  8 MB
  unsigned short* Vt  = (unsigned short*)(ws + 33554432);   //  8 MB
  unsigned short* Qjl = (unsigned short*)(ws + 41943040);   //  4 MB
  unsigned short* Kjl = (unsigned short*)(ws + 46137344);   //  4 MB
  unsigned short* AO  = (unsigned short*)(ws + 50331648);   //  8 MB
  unsigned short* Spb = (unsigned short*)(ws + 58720256);   //  4 KB

  cvt_kernel<<<2048, 256, 0, stream>>>(hidden, hB, B_ * S_ * D_);
  cvt_kernel<<<8, 256, 0, stream>>>(S_proj, Spb, KJL * HD_);
  tcvt_kernel<<<dim3(N3 / 32, D_ / 32), dim3(32, 8), 0, stream>>>(W_attn, WaT, D_, N3);
  tcvt_kernel<<<dim3(D_ / 32, D_ / 32), dim3(32, 8), 0, stream>>>(W_proj, WpT, D_, D_);
  qkv_gemm_kernel<<<dim3(N3 / 128, (B_ * S_) / 128), 256, 0, stream>>>(
      hB, WaT, b_attn, Qh, Kh, Vt);
  jl_kernel<<<256, 256, 0, stream>>>(Qh, Spb, Qjl, 0.125f);  // fold 1/sqrt(64)
  jl_kernel<<<256, 256, 0, stream>>>(Kh, Spb, Kjl, 1.0f);
  attn_kernel<<<dim3(S_ / 128, H_, B_), 256, 0, stream>>>(Qjl, Kjl, Vt, AO);
  proj_gemm_kernel<<<dim3(D_ / 128, (B_ * S_) / 128), 256, 0, stream>>>(
      AO, WpT, b_proj, out);
}